// Round 1
// baseline (359.821 us; speedup 1.0000x reference)
//
#include <hip/hip_runtime.h>

// SMPL GAT encoder, fully fused, one node per thread.
// Graph insight: self-loops + tree edges => each destination has <=2 in-edges
// (self + parent) => segment softmax is a 2-way softmax.
// All weights are read via wave-uniform global loads (compiler emits s_load ->
// SGPR operands, scalar cache) so the LDS pipe only carries the per-node h
// exchange. LDS ~24 KB, 1 node/thread, 8 frames/block.
//
// R1 change: epilogue store coalescing. Old: each thread stored its node's
// 96 B directly -> lanes at 96-B stride -> every store instr touched 64
// distinct cache lines with 16-B partials (4x L2 write requests). New: blend
// result staged into reused s_h (stride-28 rows, bank-clean), then fully
// coalesced lane-contiguous float4 stores.

#define JNT 24               // joints per frame
#define FPB 8                // frames per block
#define TPB (FPB*JNT)        // 192 threads = 3 waves
#define NPB (FPB*JNT)        // 192 nodes per block (1 per thread)

// SMPL parent table
__constant__ int c_par[JNT] = {-1,0,0,0,1,2,3,4,5,6,7,8,9,9,9,12,13,14,16,17,18,19,20,21};

// swizzled row offset for s_h: stride 28 dwords, +4 dwords every 8 rows.
// Makes the per-lane b128 publish/consume hit distinct 4-bank groups.
__device__ __forceinline__ int hoff(int r) { return r*28 + ((r>>3)<<2); }

#define SH_SIZE 5468   // hoff(NPB-1)+28 = 191*28 + 92 + 28; also >= 192*28=5376 (out staging)

__global__ __launch_bounds__(TPB, 5)
void gat_encoder(const float* __restrict__ src,
                 const float* __restrict__ W_pre,
                 const float* __restrict__ b_pre,
                 const float* __restrict__ W_gat,
                 const float* __restrict__ att_src,
                 const float* __restrict__ att_dst,
                 const float* __restrict__ b_gat,
                 float* __restrict__ out)
{
    __shared__ float s_src[NPB*3];                 // staged input (coalesced)
    __shared__ int   s_par[JNT];
    __shared__ __align__(16) float s_h[SH_SIZE];   // per node: h[0..23], a_src[24..26]; later: out staging

    const int tid = threadIdx.x;

    if (tid < JNT) s_par[tid] = c_par[tid];
    {
        const float* sg = src + (size_t)blockIdx.x * (NPB*3);
        s_src[tid]         = sg[tid];
        s_src[tid +   TPB] = sg[tid +   TPB];
        s_src[tid + 2*TPB] = sg[tid + 2*TPB];
    }
    __syncthreads();

    const float s0 = s_src[tid*3+0], s1 = s_src[tid*3+1], s2 = s_src[tid*3+2];

    // ---- h = relu(src*W_pre + b_pre) * W_gat, x kept transient ----
    float h[JNT];
    #pragma unroll
    for (int o = 0; o < JNT; ++o) h[o] = 0.f;

    #pragma unroll 2
    for (int k = 0; k < JNT; ++k) {
        // wave-uniform loads -> s_load -> SGPR operands
        const float w0 = W_pre[k], w1 = W_pre[24+k], w2 = W_pre[48+k];
        const float bb = b_pre[k];
        float x = fmaf(s0, w0, fmaf(s1, w1, fmaf(s2, w2, bb)));
        x = fmaxf(x, 0.f);
        #pragma unroll
        for (int o = 0; o < JNT; ++o)
            h[o] = fmaf(x, W_gat[k*JNT + o], h[o]);
    }

    // ---- attention dots (att vectors uniform -> SGPRs) ----
    float as[3], ad[3];
    #pragma unroll
    for (int hd = 0; hd < 3; ++hd) {
        float a = 0.f, d = 0.f;
        #pragma unroll
        for (int o = 0; o < 8; ++o) {
            a = fmaf(h[hd*8+o], att_src[hd*8+o], a);
            d = fmaf(h[hd*8+o], att_dst[hd*8+o], d);
        }
        as[hd] = a; ad[hd] = d;
    }

    // ---- publish h + a_src for children ----
    float* hr = &s_h[hoff(tid)];
    #pragma unroll
    for (int q = 0; q < 6; ++q)
        ((float4*)hr)[q] = make_float4(h[q*4+0], h[q*4+1], h[q*4+2], h[q*4+3]);
    hr[24] = as[0]; hr[25] = as[1]; hr[26] = as[2];
    __syncthreads();

    // ---- 2-way softmax vs parent ----
    const int  f    = tid / JNT;
    const int  j    = tid - f*JNT;
    const int  par  = s_par[j];
    const bool hasp = (par >= 0);
    const float* hp = &s_h[hoff(f*JNT + (hasp ? par : j))];

    float ws[3], wpv[3];
    #pragma unroll
    for (int hd = 0; hd < 3; ++hd) {
        float es = as[hd] + ad[hd];      es = es < 0.f ? 0.2f*es : es;
        float ep = hp[24+hd] + ad[hd];   ep = ep < 0.f ? 0.2f*ep : ep;
        float m  = hasp ? fmaxf(es, ep) : es;
        float e1 = __expf(es - m);
        float e2 = hasp ? __expf(ep - m) : 0.f;
        float r  = 1.f / (e1 + e2);
        ws[hd] = e1*r; wpv[hd] = e2*r;
    }

    // ---- blend, bias (uniform), relu -> registers ----
    float r[JNT];
    #pragma unroll
    for (int q = 0; q < 6; ++q) {
        const int hd = q >> 1;
        const float4 p4 = ((const float4*)hp)[q];
        r[q*4+0] = fmaxf(fmaf(wpv[hd], p4.x, fmaf(ws[hd], h[q*4+0], b_gat[q*4+0])), 0.f);
        r[q*4+1] = fmaxf(fmaf(wpv[hd], p4.y, fmaf(ws[hd], h[q*4+1], b_gat[q*4+1])), 0.f);
        r[q*4+2] = fmaxf(fmaf(wpv[hd], p4.z, fmaf(ws[hd], h[q*4+2], b_gat[q*4+2])), 0.f);
        r[q*4+3] = fmaxf(fmaf(wpv[hd], p4.w, fmaf(ws[hd], h[q*4+3], b_gat[q*4+3])), 0.f);
    }

    // ---- stage into LDS (reuse s_h; stride 28 dwords => -4 mod 32 banks,
    //      writes cycle all 8 bank groups) ----
    __syncthreads();   // all parent-h reads done; safe to overwrite s_h
    {
        float* orow = &s_h[tid*28];
        #pragma unroll
        for (int q = 0; q < 6; ++q)
            ((float4*)orow)[q] = make_float4(r[q*4+0], r[q*4+1], r[q*4+2], r[q*4+3]);
    }
    __syncthreads();

    // ---- fully coalesced stores: lane t writes float4 at t*16 + k*3072 ----
    {
        const int n0 = (tid*4) / JNT;        // 24 | 4-chunks: float4 never straddles a node
        const int c0 = (tid*4) % JNT;
        const float* rb = &s_h[n0*28 + c0];
        float* og = out + (size_t)blockIdx.x * (NPB*JNT) + tid*4;
        #pragma unroll
        for (int k = 0; k < 6; ++k) {
            const float4 v = *(const float4*)(rb + k*896);   // 32 nodes * 28 dwords per 768-dword chunk
            *(float4*)(og + k*768) = v;
        }
    }
}

extern "C" void kernel_launch(void* const* d_in, const int* in_sizes, int n_in,
                              void* d_out, int out_size, void* d_ws, size_t ws_size,
                              hipStream_t stream) {
    const float* src     = (const float*)d_in[0];
    const float* W_pre   = (const float*)d_in[1];
    const float* b_pre   = (const float*)d_in[2];
    const float* W_gat   = (const float*)d_in[3];
    const float* att_src = (const float*)d_in[4];
    const float* att_dst = (const float*)d_in[5];
    const float* b_gat   = (const float*)d_in[6];
    float* out = (float*)d_out;

    const int frames = 64 * 2048;        // N * L
    const int blocks = frames / FPB;     // 16384, exact
    gat_encoder<<<dim3(blocks), dim3(TPB), 0, stream>>>(
        src, W_pre, b_pre, W_gat, att_src, att_dst, b_gat, out);
}